// Round 7
// baseline (23.735 us; speedup 1.0000x reference)
//
#include <hip/hip_runtime.h>
#include <math.h>

#define N_ 2
#define C_ 32
#define X_ 48
#define Y_ 48
#define Z_ 24
#define M_ (X_*Y_*Z_)   // 55296

#define TX_ 2
#define TY_ 4
#define TZ_ 12
#define HX_ (TX_+2)          // 4
#define HY_ (TY_+2)          // 6
#define HZ_ (TZ_+2)          // 14
#define HVOX_ (HX_*HY_*HZ_)  // 336 halo voxels
#define TVOX_ (TX_*TY_*TZ_)  // 96 output voxels
#define THREADS_ 192         // 2 threads per output voxel (channel halves)
#define NXT_ (X_/TX_)        // 24
#define NYT_ (Y_/TY_)        // 12
#define NZT_ (Z_/TZ_)        // 2
#define P1_ITERS_ ((HVOX_*4)/THREADS_)   // 1344/192 = 7, exact

typedef _Float16 h2 __attribute__((ext_vector_type(2)));

#if __has_builtin(__builtin_amdgcn_fdot2)
__device__ __forceinline__ float dot2(h2 a, h2 b, float c) {
    return __builtin_amdgcn_fdot2(a, b, c, false);
}
#else
__device__ __forceinline__ float dot2(h2 a, h2 b, float c) {
    return fmaf((float)a[1], (float)b[1], fmaf((float)a[0], (float)b[0], c));
}
#endif

// Fused kernel, z-split tiles for balance + residency.
//  Phase 1: per-quad halo staging (4 threads/voxel, 8 ch each; 7 exact
//           iterations, no dead lanes). Norm via 2 shfl_xor across the 4
//           quad-lanes. fp16 voxel-major in LDS, XOR-swizzled 16B quads.
//  Phase 2: 2 threads/voxel; f0 normalized on the fly; 27 neighbor dots from
//           LDS; online no-max softmax (|logit| <= exp(logit_scale) = 14.29).
__global__ __launch_bounds__(THREADS_, 6) void fused_kernel(
    const float* __restrict__ f0, const float* __restrict__ f1,
    const float* __restrict__ logit_scale, float* __restrict__ out)
{
    __shared__ int4 lds[HVOX_ * 4];   // 21,504 B

    const int tid = threadIdx.x;
    const int bid = blockIdx.x;
    const int n   = bid / (NXT_ * NYT_ * NZT_);
    int rem = bid - n * (NXT_ * NYT_ * NZT_);
    const int zt = rem % NZT_;  rem /= NZT_;
    const int xt = rem % NXT_;
    const int yt = rem / NXT_;
    const int x0 = xt * TX_;
    const int y0 = yt * TY_;
    const int z0 = zt * TZ_;

    // ---------------- Phase 1: f1 halo -> normalized fp16 in LDS ----------
    const float* f1b = f1 + (size_t)n * C_ * M_;
#pragma unroll 2
    for (int it = 0; it < P1_ITERS_; ++it) {
        int tt = it * THREADS_ + tid;
        int h = tt >> 2;             // halo voxel (lanes 4k..4k+3 share h)
        int q = tt & 3;              // channel quarter (8 ch)
        int hx = h / (HY_ * HZ_);
        int rh = h - hx * (HY_ * HZ_);
        int hy = rh / HZ_;
        int hz = rh - hy * HZ_;
        int ggx = min(max(x0 - 1 + hx, 0), X_ - 1);
        int ggy = min(max(y0 - 1 + hy, 0), Y_ - 1);
        int ggz = min(max(z0 - 1 + hz, 0), Z_ - 1);
        int ggm = (ggx * Y_ + ggy) * Z_ + ggz;

        const float* p = f1b + (size_t)q * 8 * M_ + ggm;
        float b[8];
        float s = 0.f;
#pragma unroll
        for (int i = 0; i < 8; ++i) {
            b[i] = p[(size_t)i * M_];
            s = fmaf(b[i], b[i], s);
        }
        s += __shfl_xor(s, 1, 64);   // combine the 4 quad-lanes of this voxel
        s += __shfl_xor(s, 2, 64);
        float rs = 1.0f / (sqrtf(s) + 1e-7f);

        union { int4 qq; h2 hh[4]; } u;
#pragma unroll
        for (int e = 0; e < 4; ++e) {
            h2 v2;
            v2[0] = (_Float16)(b[2 * e]     * rs);
            v2[1] = (_Float16)(b[2 * e + 1] * rs);
            u.hh[e] = v2;
        }
        lds[h * 4 + (q ^ ((h >> 1) & 3))] = u.qq;   // bank swizzle
    }
    __syncthreads();

    // ---------------- Phase 2: per-voxel dots + softmax --------------------
    const int lane = tid & 63;
    const int w    = tid >> 6;
    const int hi   = lane >> 5;          // channel half
    const int slot = lane & 31;
    const int ov   = w * 32 + slot;      // 0..95, tz-consecutive
    const int tz   = ov % TZ_;
    const int txy  = ov / TZ_;
    const int ty   = txy % TY_;
    const int tx   = txy / TY_;
    const int gx = x0 + tx, gy = y0 + ty, gz = z0 + tz;
    const int gm = (gx * Y_ + gy) * Z_ + gz;

    // own 16 raw f0 channels; cross-half norm reduce
    const float* p0 = f0 + (size_t)n * C_ * M_ + (size_t)hi * 16 * M_ + gm;
    float a[16];
    float s0 = 0.f;
#pragma unroll
    for (int i = 0; i < 16; ++i) {
        a[i] = p0[(size_t)i * M_];
        s0 = fmaf(a[i], a[i], s0);
    }
    s0 += __shfl_xor(s0, 32, 64);
    float rs0 = __expf(logit_scale[0]) / (sqrtf(s0) + 1e-7f);
    h2 A[8];
#pragma unroll
    for (int i = 0; i < 8; ++i) {
        h2 v;
        v[0] = (_Float16)(a[2 * i]     * rs0);
        v[1] = (_Float16)(a[2 * i + 1] * rs0);
        A[i] = v;
    }

    float S = 0.f, FX = 0.f, FY = 0.f, FZ = 0.f;
#pragma unroll
    for (int i = 0; i < 3; ++i)
#pragma unroll
    for (int j = 0; j < 3; ++j)
#pragma unroll
    for (int k = 0; k < 3; ++k) {
        bool val = (gx + i - 1 >= 0) & (gx + i - 1 < X_) &
                   (gy + j - 1 >= 0) & (gy + j - 1 < Y_) &
                   (gz + k - 1 >= 0) & (gz + k - 1 < Z_);
        // halo indices: clamping already applied at staging time
        int v = ((tx + i) * HY_ + (ty + j)) * HZ_ + (tz + k);
        union { int4 qq; h2 hh[4]; } B0, B1;
        int vx = (v >> 1) & 3;
        B0.qq = lds[v * 4 + ((2 * hi)     ^ vx)];
        B1.qq = lds[v * 4 + ((2 * hi + 1) ^ vx)];
        float d = 0.f;
#pragma unroll
        for (int e = 0; e < 4; ++e) d = dot2(A[e],     B0.hh[e], d);
#pragma unroll
        for (int e = 0; e < 4; ++e) d = dot2(A[4 + e], B1.hh[e], d);
        d += __shfl_xor(d, 32, 64);          // full 32-channel dot
        d = val ? d : 0.0f;                  // invalid -> logit exactly 0
        float e_ = __expf(d);                // bounded: |logit| <= 14.29
        S += e_;
        if (i == 0) FX -= e_; else if (i == 2) FX += e_;
        if (j == 0) FY -= e_; else if (j == 2) FY += e_;
        if (k == 0) FZ -= e_; else if (k == 2) FZ += e_;
    }

    if (hi == 0) {
        float inv = 1.0f / S;
        size_t ob = ((size_t)n * M_ + gm) * 3;
        out[ob + 0] = FX * inv;
        out[ob + 1] = FY * inv;
        out[ob + 2] = FZ * inv;
    }
}

extern "C" void kernel_launch(void* const* d_in, const int* in_sizes, int n_in,
                              void* d_out, int out_size, void* d_ws, size_t ws_size,
                              hipStream_t stream) {
    const float* f0 = (const float*)d_in[0];
    const float* f1 = (const float*)d_in[1];
    const float* ls = (const float*)d_in[3];
    float* out = (float*)d_out;

    const int blocks = NXT_ * NYT_ * NZT_ * N_;   // 1152
    fused_kernel<<<blocks, THREADS_, 0, stream>>>(f0, f1, ls, out);
}

// Round 8
// 20.964 us; speedup vs baseline: 1.1322x; 1.1322x over previous
//
#include <hip/hip_runtime.h>
#include <math.h>

#define N_ 2
#define C_ 32
#define X_ 48
#define Y_ 48
#define Z_ 24
#define M_ (X_*Y_*Z_)   // 55296

#define TX_ 2
#define TY_ 4
#define HX_ (TX_+2)          // 4
#define HY_ (TY_+2)          // 6
#define HVOX_ (HX_*HY_*Z_)   // 576 halo voxels
#define TVOX_ (TX_*TY_*Z_)   // 192 output voxels
#define THREADS_ 384         // 2 threads per output voxel (channel halves)
#define NXT_ (X_/TX_)        // 24
#define NYT_ (Y_/TY_)        // 12
#define P1_ITERS_ ((HVOX_*4)/THREADS_)   // 2304/384 = 6, exact

typedef _Float16 h2 __attribute__((ext_vector_type(2)));

#if __has_builtin(__builtin_amdgcn_fdot2)
__device__ __forceinline__ float dot2(h2 a, h2 b, float c) {
    return __builtin_amdgcn_fdot2(a, b, c, false);
}
#else
__device__ __forceinline__ float dot2(h2 a, h2 b, float c) {
    return fmaf((float)a[1], (float)b[1], fmaf((float)a[0], (float)b[0], c));
}
#endif

// Round-5 structure (best so far), phase 1 reworked to per-quad staging:
//  Phase 1: 4 threads per halo voxel, 8 channels each -> 6 exact iterations,
//           short dep chains, low register pressure. Norm via 2 shfl_xor
//           across the quad-lanes. fp16 voxel-major in LDS, XOR-swizzled 16B
//           quads (per-wave writes cover contiguous 1KB -> conflict-free).
//  Phase 2: 2 threads/voxel (channel halves); f0 normalized on the fly with
//           exp(logit_scale) folded in; 27 neighbor dots from LDS; online
//           no-max softmax (|logit| <= exp(logit_scale) = 14.29, exp safe).
__global__ __launch_bounds__(THREADS_, 3) void fused_kernel(
    const float* __restrict__ f0, const float* __restrict__ f1,
    const float* __restrict__ logit_scale, float* __restrict__ out)
{
    __shared__ int4 lds[HVOX_ * 4];   // 36,864 B

    const int tid = threadIdx.x;
    const int bid = blockIdx.x;
    const int n   = bid / (NXT_ * NYT_);
    const int rem = bid - n * (NXT_ * NYT_);
    const int xt  = rem % NXT_;
    const int yt  = rem / NXT_;
    const int x0  = xt * TX_;
    const int y0  = yt * TY_;

    // ---------------- Phase 1: f1 halo -> normalized fp16 in LDS ----------
    const float* f1b = f1 + (size_t)n * C_ * M_;
#pragma unroll
    for (int it = 0; it < P1_ITERS_; ++it) {
        int tt = it * THREADS_ + tid;
        int h = tt >> 2;             // halo voxel (lanes 4k..4k+3 share h)
        int q = tt & 3;              // channel quarter (8 ch)
        int hx = h / (HY_ * Z_);
        int rh = h - hx * (HY_ * Z_);
        int hy = rh / Z_;
        int hz = rh - hy * Z_;
        int ggx = min(max(x0 - 1 + hx, 0), X_ - 1);
        int ggy = min(max(y0 - 1 + hy, 0), Y_ - 1);
        int ggm = (ggx * Y_ + ggy) * Z_ + hz;

        const float* p = f1b + (size_t)q * 8 * M_ + ggm;
        float b[8];
        float s = 0.f;
#pragma unroll
        for (int i = 0; i < 8; ++i) {
            b[i] = p[(size_t)i * M_];
            s = fmaf(b[i], b[i], s);
        }
        s += __shfl_xor(s, 1, 64);   // combine the 4 quad-lanes of this voxel
        s += __shfl_xor(s, 2, 64);
        float rs = 1.0f / (sqrtf(s) + 1e-7f);

        union { int4 qq; h2 hh[4]; } u;
#pragma unroll
        for (int e = 0; e < 4; ++e) {
            h2 v2;
            v2[0] = (_Float16)(b[2 * e]     * rs);
            v2[1] = (_Float16)(b[2 * e + 1] * rs);
            u.hh[e] = v2;
        }
        lds[h * 4 + (q ^ ((h >> 1) & 3))] = u.qq;   // bank swizzle
    }
    __syncthreads();

    // ---------------- Phase 2: per-voxel dots + softmax --------------------
    const int lane = tid & 63;
    const int w    = tid >> 6;
    const int hi   = lane >> 5;          // channel half
    const int slot = lane & 31;
    const int ov   = w * 32 + slot;      // 0..191, tz-consecutive
    const int tz   = ov % Z_;
    const int txy  = ov / Z_;
    const int ty   = txy % TY_;
    const int tx   = txy / TY_;
    const int gx = x0 + tx, gy = y0 + ty, gz = tz;
    const int gm = (gx * Y_ + gy) * Z_ + gz;

    // own 16 raw f0 channels; cross-half norm reduce
    const float* p0 = f0 + (size_t)n * C_ * M_ + (size_t)hi * 16 * M_ + gm;
    float a[16];
    float s0 = 0.f;
#pragma unroll
    for (int i = 0; i < 16; ++i) {
        a[i] = p0[(size_t)i * M_];
        s0 = fmaf(a[i], a[i], s0);
    }
    s0 += __shfl_xor(s0, 32, 64);
    float rs0 = __expf(logit_scale[0]) / (sqrtf(s0) + 1e-7f);
    h2 A[8];
#pragma unroll
    for (int i = 0; i < 8; ++i) {
        h2 v;
        v[0] = (_Float16)(a[2 * i]     * rs0);
        v[1] = (_Float16)(a[2 * i + 1] * rs0);
        A[i] = v;
    }

    float S = 0.f, FX = 0.f, FY = 0.f, FZ = 0.f;
#pragma unroll
    for (int i = 0; i < 3; ++i)
#pragma unroll
    for (int j = 0; j < 3; ++j)
#pragma unroll
    for (int k = 0; k < 3; ++k) {
        bool val = (gx + i - 1 >= 0) & (gx + i - 1 < X_) &
                   (gy + j - 1 >= 0) & (gy + j - 1 < Y_) &
                   (gz + k - 1 >= 0) & (gz + k - 1 < Z_);
        int hz = min(max(tz + k - 1, 0), Z_ - 1);
        int v  = (tx + i) * (HY_ * Z_) + (ty + j) * Z_ + hz;
        union { int4 qq; h2 hh[4]; } B0, B1;
        int vx = (v >> 1) & 3;
        B0.qq = lds[v * 4 + ((2 * hi)     ^ vx)];
        B1.qq = lds[v * 4 + ((2 * hi + 1) ^ vx)];
        float d = 0.f;
#pragma unroll
        for (int e = 0; e < 4; ++e) d = dot2(A[e],     B0.hh[e], d);
#pragma unroll
        for (int e = 0; e < 4; ++e) d = dot2(A[4 + e], B1.hh[e], d);
        d += __shfl_xor(d, 32, 64);          // full 32-channel dot
        d = val ? d : 0.0f;                  // invalid -> logit exactly 0
        float e_ = __expf(d);                // bounded: |logit| <= 14.29
        S += e_;
        if (i == 0) FX -= e_; else if (i == 2) FX += e_;
        if (j == 0) FY -= e_; else if (j == 2) FY += e_;
        if (k == 0) FZ -= e_; else if (k == 2) FZ += e_;
    }

    if (hi == 0) {
        float inv = 1.0f / S;
        size_t ob = ((size_t)n * M_ + gm) * 3;
        out[ob + 0] = FX * inv;
        out[ob + 1] = FY * inv;
        out[ob + 2] = FZ * inv;
    }
}

extern "C" void kernel_launch(void* const* d_in, const int* in_sizes, int n_in,
                              void* d_out, int out_size, void* d_ws, size_t ws_size,
                              hipStream_t stream) {
    const float* f0 = (const float*)d_in[0];
    const float* f1 = (const float*)d_in[1];
    const float* ls = (const float*)d_in[3];
    float* out = (float*)d_out;

    const int blocks = NXT_ * NYT_ * N_;     // 576
    fused_kernel<<<blocks, THREADS_, 0, stream>>>(f0, f1, ls, out);
}

// Round 9
// 18.265 us; speedup vs baseline: 1.2995x; 1.1477x over previous
//
#include <hip/hip_runtime.h>
#include <math.h>

#define N_ 2
#define C_ 32
#define X_ 48
#define Y_ 48
#define Z_ 24
#define M_ (X_*Y_*Z_)   // 55296
#define NM_ (N_*M_)     // 110592

#define TX_ 2
#define TY_ 4
#define HX_ (TX_+2)          // 4
#define HY_ (TY_+2)          // 6
#define HVOX_ (HX_*HY_*Z_)   // 576 halo voxels
#define TVOX_ (TX_*TY_*Z_)   // 192 output voxels
#define THREADS_ 384         // 2 threads per output voxel (channel halves)
#define NXT_ (X_/TX_)        // 24
#define NYT_ (Y_/TY_)        // 12

typedef _Float16 h2 __attribute__((ext_vector_type(2)));

#if __has_builtin(__builtin_amdgcn_fdot2)
__device__ __forceinline__ float dot2(h2 a, h2 b, float c) {
    return __builtin_amdgcn_fdot2(a, b, c, false);
}
#else
__device__ __forceinline__ float dot2(h2 a, h2 b, float c) {
    return fmaf((float)a[1], (float)b[1], fmaf((float)a[0], (float)b[0], c));
}
#endif

// Single fused kernel (round-5 structure, best measured: 18.2 us). Per block:
//  Phase 1: load raw f1 halo (HX_*HY_*24 voxels, clamped coords), L2-normalize,
//           store fp16 voxel-major in LDS with XOR-swizzled 16B quads.
//           Wave lanes cover consecutive halo voxels -> 256B contiguous
//           segments per load instruction (coalescing is why this beats the
//           per-quad variant of round 8).
//  Phase 2: per output voxel (2 threads = channel halves): normalize f0 on the
//           fly (fold exp(logit_scale)), 27 neighbor dots from LDS, online
//           no-max softmax (logits bounded by exp(logit_scale)=14.29).
__global__ __launch_bounds__(THREADS_, 3) void fused_kernel(
    const float* __restrict__ f0, const float* __restrict__ f1,
    const float* __restrict__ logit_scale, float* __restrict__ out)
{
    __shared__ int4 lds[HVOX_ * 4];   // 36,864 B

    const int tid = threadIdx.x;
    const int bid = blockIdx.x;
    const int n   = bid / (NXT_ * NYT_);
    const int rem = bid - n * (NXT_ * NYT_);
    const int xt  = rem % NXT_;
    const int yt  = rem / NXT_;
    const int x0  = xt * TX_;
    const int y0  = yt * TY_;

    // ---------------- Phase 1: f1 halo -> normalized fp16 in LDS ----------
    const float* f1b = f1 + (size_t)n * C_ * M_;
    for (int h = tid; h < HVOX_; h += THREADS_) {
        int hx = h / (HY_ * Z_);
        int rh = h - hx * (HY_ * Z_);
        int hy = rh / Z_;
        int hz = rh - hy * Z_;
        int gx = min(max(x0 - 1 + hx, 0), X_ - 1);
        int gy = min(max(y0 - 1 + hy, 0), Y_ - 1);
        int gm = (gx * Y_ + gy) * Z_ + hz;

        float b[C_];
        float s = 0.f;
#pragma unroll
        for (int c = 0; c < C_; ++c) {
            b[c] = f1b[(size_t)c * M_ + gm];
            s = fmaf(b[c], b[c], s);
        }
        float rs = 1.0f / (sqrtf(s) + 1e-7f);
#pragma unroll
        for (int q = 0; q < 4; ++q) {            // quad q holds channels 8q..8q+7
            union { int4 qq; h2 hh[4]; } u;
#pragma unroll
            for (int e = 0; e < 4; ++e) {
                h2 v2;
                v2[0] = (_Float16)(b[8 * q + 2 * e]     * rs);
                v2[1] = (_Float16)(b[8 * q + 2 * e + 1] * rs);
                u.hh[e] = v2;
            }
            lds[h * 4 + (q ^ ((h >> 1) & 3))] = u.qq;   // bank swizzle
        }
    }
    __syncthreads();

    // ---------------- Phase 2: per-voxel dots + softmax --------------------
    const int lane = tid & 63;
    const int w    = tid >> 6;
    const int hi   = lane >> 5;          // channel half
    const int slot = lane & 31;
    const int ov   = w * 32 + slot;      // 0..191, tz-consecutive
    const int tz   = ov % Z_;
    const int txy  = ov / Z_;
    const int ty   = txy % TY_;
    const int tx   = txy / TY_;
    const int gx = x0 + tx, gy = y0 + ty, gz = tz;
    const int gm = (gx * Y_ + gy) * Z_ + gz;

    // own 16 raw f0 channels; cross-half norm reduce
    const float* p0 = f0 + (size_t)n * C_ * M_ + (size_t)hi * 16 * M_ + gm;
    float a[16];
    float s0 = 0.f;
#pragma unroll
    for (int i = 0; i < 16; ++i) {
        a[i] = p0[(size_t)i * M_];
        s0 = fmaf(a[i], a[i], s0);
    }
    s0 += __shfl_xor(s0, 32, 64);
    float rs0 = __expf(logit_scale[0]) / (sqrtf(s0) + 1e-7f);
    h2 A[8];
#pragma unroll
    for (int i = 0; i < 8; ++i) {
        h2 v;
        v[0] = (_Float16)(a[2 * i]     * rs0);
        v[1] = (_Float16)(a[2 * i + 1] * rs0);
        A[i] = v;
    }

    float S = 0.f, FX = 0.f, FY = 0.f, FZ = 0.f;
#pragma unroll
    for (int i = 0; i < 3; ++i)
#pragma unroll
    for (int j = 0; j < 3; ++j)
#pragma unroll
    for (int k = 0; k < 3; ++k) {
        bool val = (gx + i - 1 >= 0) & (gx + i - 1 < X_) &
                   (gy + j - 1 >= 0) & (gy + j - 1 < Y_) &
                   (gz + k - 1 >= 0) & (gz + k - 1 < Z_);
        int hz = min(max(tz + k - 1, 0), Z_ - 1);
        int v  = (tx + i) * (HY_ * Z_) + (ty + j) * Z_ + hz;
        union { int4 qq; h2 hh[4]; } B0, B1;
        int vx = (v >> 1) & 3;
        B0.qq = lds[v * 4 + ((2 * hi)     ^ vx)];
        B1.qq = lds[v * 4 + ((2 * hi + 1) ^ vx)];
        float d = 0.f;
#pragma unroll
        for (int e = 0; e < 4; ++e) d = dot2(A[e],     B0.hh[e], d);
#pragma unroll
        for (int e = 0; e < 4; ++e) d = dot2(A[4 + e], B1.hh[e], d);
        d += __shfl_xor(d, 32, 64);          // full 32-channel dot
        d = val ? d : 0.0f;                  // invalid -> logit exactly 0
        float e_ = __expf(d);                // bounded: |logit| <= 14.29
        S += e_;
        if (i == 0) FX -= e_; else if (i == 2) FX += e_;
        if (j == 0) FY -= e_; else if (j == 2) FY += e_;
        if (k == 0) FZ -= e_; else if (k == 2) FZ += e_;
    }

    if (hi == 0) {
        float inv = 1.0f / S;
        size_t ob = ((size_t)n * M_ + gm) * 3;
        out[ob + 0] = FX * inv;
        out[ob + 1] = FY * inv;
        out[ob + 2] = FZ * inv;
    }
}

extern "C" void kernel_launch(void* const* d_in, const int* in_sizes, int n_in,
                              void* d_out, int out_size, void* d_ws, size_t ws_size,
                              hipStream_t stream) {
    const float* f0 = (const float*)d_in[0];
    const float* f1 = (const float*)d_in[1];
    const float* ls = (const float*)d_in[3];
    float* out = (float*)d_out;

    const int blocks = NXT_ * NYT_ * N_;     // 576
    fused_kernel<<<blocks, THREADS_, 0, stream>>>(f0, f1, ls, out);
}

// Round 10
// 17.129 us; speedup vs baseline: 1.3857x; 1.0663x over previous
//
#include <hip/hip_runtime.h>
#include <math.h>

#define N_ 2
#define C_ 32
#define X_ 48
#define Y_ 48
#define Z_ 24
#define M_ (X_*Y_*Z_)   // 55296

#define TX_ 2
#define TY_ 2
#define HX_ (TX_+2)          // 4
#define HY_ (TY_+2)          // 4
#define HVOX_ (HX_*HY_*Z_)   // 384 halo voxels
#define TVOX_ (TX_*TY_*Z_)   // 96 output voxels
#define THREADS_ 192         // 2 threads per output voxel (channel halves)
#define NXT_ (X_/TX_)        // 24
#define NYT_ (Y_/TY_)        // 24

typedef _Float16 h2 __attribute__((ext_vector_type(2)));

#if __has_builtin(__builtin_amdgcn_fdot2)
__device__ __forceinline__ float dot2(h2 a, h2 b, float c) {
    return __builtin_amdgcn_fdot2(a, b, c, false);
}
#else
__device__ __forceinline__ float dot2(h2 a, h2 b, float c) {
    return fmaf((float)a[1], (float)b[1], fmaf((float)a[0], (float)b[0], c));
}
#endif

// R5 structure with smaller tiles for load balance (the only change):
//  - 1152 blocks (4.5/CU, tail 33% -> 11%), 24.6 KB LDS (-> ~6 resident/CU)
//  - phase 1: per-voxel staging (1 thread x 32 ch), wave lanes cover 64
//    consecutive halo voxels -> coalesced; exactly 2 iterations, no tail
//  - phase 2: identical to R5 (2 threads/voxel, swizzled LDS dots, online
//    no-max softmax; |logit| <= exp(logit_scale) = 14.29 so exp is safe)
__global__ __launch_bounds__(THREADS_, 4) void fused_kernel(
    const float* __restrict__ f0, const float* __restrict__ f1,
    const float* __restrict__ logit_scale, float* __restrict__ out)
{
    __shared__ int4 lds[HVOX_ * 4];   // 24,576 B

    const int tid = threadIdx.x;
    const int bid = blockIdx.x;
    const int n   = bid / (NXT_ * NYT_);
    const int rem = bid - n * (NXT_ * NYT_);
    const int xt  = rem % NXT_;
    const int yt  = rem / NXT_;
    const int x0  = xt * TX_;
    const int y0  = yt * TY_;

    // ---------------- Phase 1: f1 halo -> normalized fp16 in LDS ----------
    const float* f1b = f1 + (size_t)n * C_ * M_;
#pragma unroll
    for (int it = 0; it < 2; ++it) {
        int h = it * THREADS_ + tid;          // HVOX_ = 2*THREADS_, exact
        int hx = h / (HY_ * Z_);
        int rh = h - hx * (HY_ * Z_);
        int hy = rh / Z_;
        int hz = rh - hy * Z_;
        int gx = min(max(x0 - 1 + hx, 0), X_ - 1);
        int gy = min(max(y0 - 1 + hy, 0), Y_ - 1);
        int gm = (gx * Y_ + gy) * Z_ + hz;

        float b[C_];
        float s = 0.f;
#pragma unroll
        for (int c = 0; c < C_; ++c) {
            b[c] = f1b[(size_t)c * M_ + gm];
            s = fmaf(b[c], b[c], s);
        }
        float rs = 1.0f / (sqrtf(s) + 1e-7f);
#pragma unroll
        for (int q = 0; q < 4; ++q) {            // quad q holds channels 8q..8q+7
            union { int4 qq; h2 hh[4]; } u;
#pragma unroll
            for (int e = 0; e < 4; ++e) {
                h2 v2;
                v2[0] = (_Float16)(b[8 * q + 2 * e]     * rs);
                v2[1] = (_Float16)(b[8 * q + 2 * e + 1] * rs);
                u.hh[e] = v2;
            }
            lds[h * 4 + (q ^ ((h >> 1) & 3))] = u.qq;   // bank swizzle
        }
    }
    __syncthreads();

    // ---------------- Phase 2: per-voxel dots + softmax --------------------
    const int lane = tid & 63;
    const int w    = tid >> 6;
    const int hi   = lane >> 5;          // channel half
    const int slot = lane & 31;
    const int ov   = w * 32 + slot;      // 0..95, tz-consecutive
    const int tz   = ov % Z_;
    const int txy  = ov / Z_;
    const int ty   = txy % TY_;
    const int tx   = txy / TY_;
    const int gx = x0 + tx, gy = y0 + ty, gz = tz;
    const int gm = (gx * Y_ + gy) * Z_ + gz;

    // own 16 raw f0 channels; cross-half norm reduce
    const float* p0 = f0 + (size_t)n * C_ * M_ + (size_t)hi * 16 * M_ + gm;
    float a[16];
    float s0 = 0.f;
#pragma unroll
    for (int i = 0; i < 16; ++i) {
        a[i] = p0[(size_t)i * M_];
        s0 = fmaf(a[i], a[i], s0);
    }
    s0 += __shfl_xor(s0, 32, 64);
    float rs0 = __expf(logit_scale[0]) / (sqrtf(s0) + 1e-7f);
    h2 A[8];
#pragma unroll
    for (int i = 0; i < 8; ++i) {
        h2 v;
        v[0] = (_Float16)(a[2 * i]     * rs0);
        v[1] = (_Float16)(a[2 * i + 1] * rs0);
        A[i] = v;
    }

    float S = 0.f, FX = 0.f, FY = 0.f, FZ = 0.f;
#pragma unroll
    for (int i = 0; i < 3; ++i)
#pragma unroll
    for (int j = 0; j < 3; ++j)
#pragma unroll
    for (int k = 0; k < 3; ++k) {
        bool val = (gx + i - 1 >= 0) & (gx + i - 1 < X_) &
                   (gy + j - 1 >= 0) & (gy + j - 1 < Y_) &
                   (gz + k - 1 >= 0) & (gz + k - 1 < Z_);
        int hz = min(max(tz + k - 1, 0), Z_ - 1);
        int v  = (tx + i) * (HY_ * Z_) + (ty + j) * Z_ + hz;
        union { int4 qq; h2 hh[4]; } B0, B1;
        int vx = (v >> 1) & 3;
        B0.qq = lds[v * 4 + ((2 * hi)     ^ vx)];
        B1.qq = lds[v * 4 + ((2 * hi + 1) ^ vx)];
        float d = 0.f;
#pragma unroll
        for (int e = 0; e < 4; ++e) d = dot2(A[e],     B0.hh[e], d);
#pragma unroll
        for (int e = 0; e < 4; ++e) d = dot2(A[4 + e], B1.hh[e], d);
        d += __shfl_xor(d, 32, 64);          // full 32-channel dot
        d = val ? d : 0.0f;                  // invalid -> logit exactly 0
        float e_ = __expf(d);                // bounded: |logit| <= 14.29
        S += e_;
        if (i == 0) FX -= e_; else if (i == 2) FX += e_;
        if (j == 0) FY -= e_; else if (j == 2) FY += e_;
        if (k == 0) FZ -= e_; else if (k == 2) FZ += e_;
    }

    if (hi == 0) {
        float inv = 1.0f / S;
        size_t ob = ((size_t)n * M_ + gm) * 3;
        out[ob + 0] = FX * inv;
        out[ob + 1] = FY * inv;
        out[ob + 2] = FZ * inv;
    }
}

extern "C" void kernel_launch(void* const* d_in, const int* in_sizes, int n_in,
                              void* d_out, int out_size, void* d_ws, size_t ws_size,
                              hipStream_t stream) {
    const float* f0 = (const float*)d_in[0];
    const float* f1 = (const float*)d_in[1];
    const float* ls = (const float*)d_in[3];
    float* out = (float*)d_out;

    const int blocks = NXT_ * NYT_ * N_;     // 1152
    fused_kernel<<<blocks, THREADS_, 0, stream>>>(f0, f1, ls, out);
}

// Round 11
// 15.985 us; speedup vs baseline: 1.4848x; 1.0715x over previous
//
#include <hip/hip_runtime.h>
#include <math.h>

#define N_ 2
#define C_ 32
#define X_ 48
#define Y_ 48
#define Z_ 24
#define M_ (X_*Y_*Z_)   // 55296

#define TX_ 2
#define TY_ 2
#define HX_ (TX_+2)          // 4
#define HY_ (TY_+2)          // 4
#define HVOX_ (HX_*HY_*Z_)   // 384 halo voxels
#define TVOX_ (TX_*TY_*Z_)   // 96 output voxels
#define THREADS_ 192         // 2 threads per output voxel (channel halves)
#define NXT_ (X_/TX_)        // 24
#define NYT_ (Y_/TY_)        // 24
#define NWG_ (NXT_*NYT_*N_)  // 1152, divisible by 8 XCDs -> chunk = 144

typedef _Float16 h2 __attribute__((ext_vector_type(2)));

#if __has_builtin(__builtin_amdgcn_fdot2)
__device__ __forceinline__ float dot2(h2 a, h2 b, float c) {
    return __builtin_amdgcn_fdot2(a, b, c, false);
}
#else
__device__ __forceinline__ float dot2(h2 a, h2 b, float c) {
    return fmaf((float)a[1], (float)b[1], fmaf((float)a[0], (float)b[0], c));
}
#endif

// R10 structure (best measured: 17.1 us) + XCD-aware block swizzle (T1).
// Consecutive dispatch-order blocks round-robin over 8 XCDs; the chunked
// remap gives each XCD a contiguous run of 144 tiles (a y-slab of one batch,
// f1 working set ~6.2 MB), so x/y-neighbor tiles sharing 75% of their halos
// run on the SAME XCD -> halo re-reads hit the 4MB XCD-private L2 instead of
// crossing to L3. Mapping is bijective (1152 = 8*144 exactly).
__global__ __launch_bounds__(THREADS_, 4) void fused_kernel(
    const float* __restrict__ f0, const float* __restrict__ f1,
    const float* __restrict__ logit_scale, float* __restrict__ out)
{
    __shared__ int4 lds[HVOX_ * 4];   // 24,576 B

    const int tid = threadIdx.x;
    const int wgid = (blockIdx.x & 7) * (NWG_ / 8) + (blockIdx.x >> 3);
    const int n   = wgid / (NXT_ * NYT_);
    const int rem = wgid - n * (NXT_ * NYT_);
    const int xt  = rem % NXT_;
    const int yt  = rem / NXT_;
    const int x0  = xt * TX_;
    const int y0  = yt * TY_;

    // ---------------- Phase 1: f1 halo -> normalized fp16 in LDS ----------
    const float* f1b = f1 + (size_t)n * C_ * M_;
#pragma unroll
    for (int it = 0; it < 2; ++it) {
        int h = it * THREADS_ + tid;          // HVOX_ = 2*THREADS_, exact
        int hx = h / (HY_ * Z_);
        int rh = h - hx * (HY_ * Z_);
        int hy = rh / Z_;
        int hz = rh - hy * Z_;
        int gx = min(max(x0 - 1 + hx, 0), X_ - 1);
        int gy = min(max(y0 - 1 + hy, 0), Y_ - 1);
        int gm = (gx * Y_ + gy) * Z_ + hz;

        float b[C_];
        float s = 0.f;
#pragma unroll
        for (int c = 0; c < C_; ++c) {
            b[c] = f1b[(size_t)c * M_ + gm];
            s = fmaf(b[c], b[c], s);
        }
        float rs = 1.0f / (sqrtf(s) + 1e-7f);
#pragma unroll
        for (int q = 0; q < 4; ++q) {            // quad q holds channels 8q..8q+7
            union { int4 qq; h2 hh[4]; } u;
#pragma unroll
            for (int e = 0; e < 4; ++e) {
                h2 v2;
                v2[0] = (_Float16)(b[8 * q + 2 * e]     * rs);
                v2[1] = (_Float16)(b[8 * q + 2 * e + 1] * rs);
                u.hh[e] = v2;
            }
            lds[h * 4 + (q ^ ((h >> 1) & 3))] = u.qq;   // bank swizzle
        }
    }
    __syncthreads();

    // ---------------- Phase 2: per-voxel dots + softmax --------------------
    const int lane = tid & 63;
    const int w    = tid >> 6;
    const int hi   = lane >> 5;          // channel half
    const int slot = lane & 31;
    const int ov   = w * 32 + slot;      // 0..95, tz-consecutive
    const int tz   = ov % Z_;
    const int txy  = ov / Z_;
    const int ty   = txy % TY_;
    const int tx   = txy / TY_;
    const int gx = x0 + tx, gy = y0 + ty, gz = tz;
    const int gm = (gx * Y_ + gy) * Z_ + gz;

    // own 16 raw f0 channels; cross-half norm reduce
    const float* p0 = f0 + (size_t)n * C_ * M_ + (size_t)hi * 16 * M_ + gm;
    float a[16];
    float s0 = 0.f;
#pragma unroll
    for (int i = 0; i < 16; ++i) {
        a[i] = p0[(size_t)i * M_];
        s0 = fmaf(a[i], a[i], s0);
    }
    s0 += __shfl_xor(s0, 32, 64);
    float rs0 = __expf(logit_scale[0]) / (sqrtf(s0) + 1e-7f);
    h2 A[8];
#pragma unroll
    for (int i = 0; i < 8; ++i) {
        h2 v;
        v[0] = (_Float16)(a[2 * i]     * rs0);
        v[1] = (_Float16)(a[2 * i + 1] * rs0);
        A[i] = v;
    }

    float S = 0.f, FX = 0.f, FY = 0.f, FZ = 0.f;
#pragma unroll
    for (int i = 0; i < 3; ++i)
#pragma unroll
    for (int j = 0; j < 3; ++j)
#pragma unroll
    for (int k = 0; k < 3; ++k) {
        bool val = (gx + i - 1 >= 0) & (gx + i - 1 < X_) &
                   (gy + j - 1 >= 0) & (gy + j - 1 < Y_) &
                   (gz + k - 1 >= 0) & (gz + k - 1 < Z_);
        int hz = min(max(tz + k - 1, 0), Z_ - 1);
        int v  = (tx + i) * (HY_ * Z_) + (ty + j) * Z_ + hz;
        union { int4 qq; h2 hh[4]; } B0, B1;
        int vx = (v >> 1) & 3;
        B0.qq = lds[v * 4 + ((2 * hi)     ^ vx)];
        B1.qq = lds[v * 4 + ((2 * hi + 1) ^ vx)];
        float d = 0.f;
#pragma unroll
        for (int e = 0; e < 4; ++e) d = dot2(A[e],     B0.hh[e], d);
#pragma unroll
        for (int e = 0; e < 4; ++e) d = dot2(A[4 + e], B1.hh[e], d);
        d += __shfl_xor(d, 32, 64);          // full 32-channel dot
        d = val ? d : 0.0f;                  // invalid -> logit exactly 0
        float e_ = __expf(d);                // bounded: |logit| <= 14.29
        S += e_;
        if (i == 0) FX -= e_; else if (i == 2) FX += e_;
        if (j == 0) FY -= e_; else if (j == 2) FY += e_;
        if (k == 0) FZ -= e_; else if (k == 2) FZ += e_;
    }

    if (hi == 0) {
        float inv = 1.0f / S;
        size_t ob = ((size_t)n * M_ + gm) * 3;
        out[ob + 0] = FX * inv;
        out[ob + 1] = FY * inv;
        out[ob + 2] = FZ * inv;
    }
}

extern "C" void kernel_launch(void* const* d_in, const int* in_sizes, int n_in,
                              void* d_out, int out_size, void* d_ws, size_t ws_size,
                              hipStream_t stream) {
    const float* f0 = (const float*)d_in[0];
    const float* f1 = (const float*)d_in[1];
    const float* ls = (const float*)d_in[3];
    float* out = (float*)d_out;

    fused_kernel<<<NWG_, THREADS_, 0, stream>>>(f0, f1, ls, out);
}